// Round 12
// baseline (123.696 us; speedup 1.0000x reference)
//
#include <hip/hip_runtime.h>
#include <hip/hip_fp16.h>
#include <math.h>

#define Bn 512
#define Ln 200
#define En 64
#define Hn 4
#define Dn 16
#define KS3 18            // Kh/Qh row stride (halves): 36 B = 9 words (9 coprime 32 -> conflict-free)
#define VS3 200           // Vt row stride (halves): 100 words (2-way = free)
#define QSC 0.36067376022224085f   // 0.25 * log2(e): folds softmax exp into 2^x

typedef _Float16 __f16;
typedef __f16 f16x4 __attribute__((ext_vector_type(4)));
typedef __f16 f16x8 __attribute__((ext_vector_type(8)));
typedef float f32x4 __attribute__((ext_vector_type(4)));

#if __has_builtin(__builtin_amdgcn_exp2f)
__device__ __forceinline__ float fexp2(float x) { return __builtin_amdgcn_exp2f(x); }
#else
__device__ __forceinline__ float fexp2(float x) { return exp2f(x); }
#endif

__device__ __forceinline__ f16x8 pack8s(float4 a, float4 b, float4 pa, float4 pb) {
    f16x8 r;
    r[0] = (__f16)(a.x + pa.x); r[1] = (__f16)(a.y + pa.y);
    r[2] = (__f16)(a.z + pa.z); r[3] = (__f16)(a.w + pa.w);
    r[4] = (__f16)(b.x + pb.x); r[5] = (__f16)(b.y + pb.y);
    r[6] = (__f16)(b.z + pb.z); r[7] = (__f16)(b.w + pb.w);
    return r;
}
__device__ __forceinline__ f16x8 pack8(float4 a, float4 b) {
    f16x8 r;
    r[0] = (__f16)a.x; r[1] = (__f16)a.y; r[2] = (__f16)a.z; r[3] = (__f16)a.w;
    r[4] = (__f16)b.x; r[5] = (__f16)b.y; r[6] = (__f16)b.z; r[7] = (__f16)b.w;
    return r;
}

// ============ Fully fused: proj + attention + pool + Wf. Block = (b, ONE head), 256 thr ============
// R11 quartered: 2048 thin blocks, ~22 KB LDS, ~halved VGPR demand -> more resident blocks,
// finer load-balance over the len in [1,200] spread. Proj is len-dependent (only nt tiles).
// Attention adapts: nquad>=3 -> wave per q-quad; nquad==2 -> 2 waves/quad split keys;
// nquad==1 -> 4-way key split. Partial softmax denominators exchanged via LDS before 1/l.
// S^T=K*Q^T C-layout == PV B-layout (proven R6-R11): no transforms. Wf epilogue fused.
__global__ __launch_bounds__(256, 6) void fused_kernel(
    const float* __restrict__ input, const int* __restrict__ mask,
    const float* __restrict__ pos_enc,
    const float* __restrict__ Wk, const float* __restrict__ bk,
    const float* __restrict__ Wv, const float* __restrict__ bv,
    const float* __restrict__ Wq, const float* __restrict__ bq,
    const float* __restrict__ Wf, const float* __restrict__ bf_,
    float* __restrict__ out)
{
    __shared__ __align__(16) __f16 Kh[Ln * KS3];    // 7.2 KB  K[t][16]
    __shared__ __align__(16) __f16 Qh[Ln * KS3];    // 7.2 KB  Q[t][16] (pre-scaled QSC)
    __shared__ __align__(16) __f16 Vt[16 * VS3];    // 6.4 KB  V^T[vd][t]
    __shared__ float lred[4][4][16];                // 1 KB   partial softmax denominators
    __shared__ float red[4][16];
    __shared__ float ph[16];
    __shared__ int cnt_red[4];

    const int tid  = threadIdx.x;
    const int b    = blockIdx.x >> 2, h = blockIdx.x & 3;
    const int wave = tid >> 6, lane = tid & 63;
    const int quad = lane >> 4, ln16 = lane & 15;

    // ---- mask load (1 per thread) issued first ----
    const int mv = (tid < Ln) ? mask[b * Ln + tid] : 0;

    // ---- weight B-fragments for THIS head (16 channels; L2-hot) + biases ----
    f16x8 bfr[3][2];
    #pragma unroll
    for (int m = 0; m < 3; ++m) {
        const float* W = (m == 0) ? Wk : (m == 1) ? Wv : Wq;
        #pragma unroll
        for (int ks = 0; ks < 2; ++ks) {
            const float4* wp = (const float4*)(W + (size_t)(h * 16 + ln16) * 64) + (ks * 8 + quad * 2);
            bfr[m][ks] = pack8(wp[0], wp[1]);
        }
    }
    const int cg = h * 16 + ln16;
    const float bkv = bk[cg], bvv = bv[cg], bqv = bq[cg];

    // ---- len before proj (proj is len-dependent: ~45% work cut at avg len) ----
    int c = (mv != 0) ? 1 : 0;
    #pragma unroll
    for (int off = 32; off; off >>= 1) c += __shfl_down(c, off, 64);
    if (lane == 0) cnt_red[wave] = c;
    __syncthreads();
    const int len = cnt_red[0] + cnt_red[1] + cnt_red[2] + cnt_red[3];
    const int nt = (len + 15) >> 4;

    // ---- projection over nt tiles; A-frags direct from global ----
    const float4* in4 = (const float4*)(input + (size_t)b * Ln * En);
    const float4* pe4 = (const float4*)pos_enc;

    for (int rt = wave; rt < nt; rt += 4) {
        const int R = rt * 16 + ln16;
        const bool rok = (R < Ln);
        f16x8 af[2];
        #pragma unroll
        for (int ks = 0; ks < 2; ++ks) {
            float4 xa = {0,0,0,0}, xb = {0,0,0,0}, pa = {0,0,0,0}, pb = {0,0,0,0};
            if (rok) {
                const int o4 = R * 16 + ks * 8 + quad * 2;
                xa = in4[o4]; xb = in4[o4 + 1];
                pa = pe4[o4]; pb = pe4[o4 + 1];
            }
            af[ks] = pack8s(xa, xb, pa, pb);
        }
        f32x4 acc[3];
        #pragma unroll
        for (int m = 0; m < 3; ++m) acc[m] = (f32x4){0,0,0,0};
        #pragma unroll
        for (int ks = 0; ks < 2; ++ks)
            #pragma unroll
            for (int m = 0; m < 3; ++m)
                acc[m] = __builtin_amdgcn_mfma_f32_16x16x32_f16(af[ks], bfr[m][ks], acc[m], 0, 0, 0);

        #pragma unroll
        for (int j = 0; j < 4; ++j) {
            const int t = rt * 16 + quad * 4 + j;
            if (t < Ln) {
                Kh[t * KS3 + ln16] = (__f16)(acc[0][j] + bkv);
                Qh[t * KS3 + ln16] = (__f16)((acc[2][j] + bqv) * QSC);
            }
        }
        const int vc0 = rt * 16 + quad * 4;
        if (vc0 < Ln) {
            f16x4 vp;
            #pragma unroll
            for (int j = 0; j < 4; ++j) vp[j] = (__f16)(acc[1][j] + bvv);
            *(f16x4*)(Vt + ln16 * VS3 + vc0) = vp;
        }
    }
    __syncthreads();   // K/Q/V visible

    // ---- attention: adaptive wave assignment ----
    const int nquad = (nt + 3) >> 2;
    int g, kh, nkh;
    if (nquad >= 3)      { g = wave;     kh = 0;         nkh = 1; }
    else if (nquad == 2) { g = wave & 1; kh = wave >> 1; nkh = 2; }
    else                 { g = 0;        kh = wave;      nkh = 4; }
    const bool active = (g < nquad);
    const int nktp = (nt + nkh - 1) / nkh;
    const int klo = kh * nktp;
    const int khi = min(klo + nktp, nt);
    const int qt0 = 4 * g;

    f32x4 o2[4];
    float l[4] = {0.f, 0.f, 0.f, 0.f};
    #pragma unroll
    for (int i = 0; i < 4; ++i) o2[i] = (f32x4){0,0,0,0};

    if (active && klo < khi) {
        f16x4 qf[4];
        #pragma unroll
        for (int i = 0; i < 4; ++i) {
            int qr = min((qt0 + i) * 16 + ln16, Ln - 1);
            qf[i] = *(const f16x4*)(Qh + qr * KS3 + quad * 4);
        }
        f16x4 kf = *(const f16x4*)(Kh + min(klo * 16 + ln16, Ln - 1) * KS3 + quad * 4);
        f16x4 vf = *(const f16x4*)(Vt + ln16 * VS3 + min(klo * 16 + quad * 4, Ln - 4));

        for (int kt = klo; kt < khi; ++kt) {
            const int krn = min((kt + 1) * 16 + ln16, Ln - 1);
            const int vcn = min((kt + 1) * 16 + quad * 4, Ln - 4);
            const f16x4 kfn = *(const f16x4*)(Kh + krn * KS3 + quad * 4);
            const f16x4 vfn = *(const f16x4*)(Vt + ln16 * VS3 + vcn);
            const int kbase = kt * 16 + quad * 4;
            f32x4 s[4];
            #pragma unroll
            for (int i = 0; i < 4; ++i)
                s[i] = __builtin_amdgcn_mfma_f32_16x16x16f16(kf, qf[i], (f32x4){0,0,0,0}, 0, 0, 0);
            f16x4 pf[4];
            #pragma unroll
            for (int i = 0; i < 4; ++i) {
                #pragma unroll
                for (int j = 0; j < 4; ++j) {
                    const bool kok = (kbase + j) < len;
                    float p = kok ? fexp2(fminf(s[i][j], 14.5f)) : 0.f;   // 2^14.5 < fp16 max
                    l[i] += p;
                    pf[i][j] = (__f16)p;
                }
            }
            #pragma unroll
            for (int i = 0; i < 4; ++i)
                o2[i] = __builtin_amdgcn_mfma_f32_16x16x16f16(vf, pf[i], o2[i], 0, 0, 0);
            kf = kfn; vf = vfn;
        }
        #pragma unroll
        for (int i = 0; i < 4; ++i) {   // sum quads -> per-query partial denominator
            l[i] += __shfl_xor(l[i], 16, 64);
            l[i] += __shfl_xor(l[i], 32, 64);
        }
    }

    // ---- exchange partial denominators across key-split waves ----
    if (lane < 16) {
        #pragma unroll
        for (int i = 0; i < 4; ++i) lred[wave][i][lane] = l[i];
    }
    __syncthreads();

    f32x4 pool = {0.f, 0.f, 0.f, 0.f};
    if (active) {
        #pragma unroll
        for (int i = 0; i < 4; ++i) {
            float lt;
            if (nkh == 1)      lt = lred[wave][i][ln16];
            else if (nkh == 2) lt = lred[g][i][ln16] + lred[g + 2][i][ln16];
            else               lt = lred[0][i][ln16] + lred[1][i][ln16]
                                  + lred[2][i][ln16] + lred[3][i][ln16];
            const float rs = ((qt0 + i) * 16 + ln16 < len) ? 1.f / lt : 0.f;
            #pragma unroll
            for (int j = 0; j < 4; ++j) pool[j] = fmaf(o2[i][j], rs, pool[j]);
        }
    }

    // ---- reduce pool over 16 q-lanes; combine 4 waves; write ----
    #pragma unroll
    for (int j = 0; j < 4; ++j) {
        #pragma unroll
        for (int off = 1; off < 16; off <<= 1) pool[j] += __shfl_xor(pool[j], off, 64);
    }
    if (ln16 == 0) {
        #pragma unroll
        for (int j = 0; j < 4; ++j) red[wave][quad * 4 + j] = pool[j];
    }
    __syncthreads();
    if (tid < 16)
        ph[tid] = (red[0][tid] + red[1][tid] + red[2][tid] + red[3][tid]) / ((float)len + 1e-8f);
    __syncthreads();

    // ---- fused final projection: partial out[b,e] over i in [h*16, h*16+16) ----
    if (tid < 64) {
        const int e = tid;
        const float* wr = Wf + (size_t)e * 64 + h * 16;
        float a = (h == 0) ? bf_[e] : 0.f;
        #pragma unroll
        for (int i = 0; i < 16; ++i) a = fmaf(wr[i], ph[i], a);
        atomicAdd(out + b * En + e, a);
    }
}

extern "C" void kernel_launch(void* const* d_in, const int* in_sizes, int n_in,
                              void* d_out, int out_size, void* d_ws, size_t ws_size,
                              hipStream_t stream) {
    const float* input   = (const float*)d_in[0];
    const int*   mask    = (const int*)  d_in[1];
    const float* pos_enc = (const float*)d_in[2];
    const float* Wk      = (const float*)d_in[3];
    const float* bk      = (const float*)d_in[4];
    const float* Wv      = (const float*)d_in[5];
    const float* bv      = (const float*)d_in[6];
    const float* Wq      = (const float*)d_in[7];
    const float* bq      = (const float*)d_in[8];
    const float* Wf      = (const float*)d_in[9];
    const float* bf      = (const float*)d_in[10];

    float* out = (float*)d_out;
    hipMemsetAsync(out, 0, (size_t)Bn * En * sizeof(float), stream);   // zero accumulator

    fused_kernel<<<Bn * Hn, 256, 0, stream>>>(input, mask, pos_enc,
                                              Wk, bk, Wv, bv, Wq, bq, Wf, bf, out);
}

// Round 13
// 122.314 us; speedup vs baseline: 1.0113x; 1.0113x over previous
//
#include <hip/hip_runtime.h>
#include <hip/hip_fp16.h>
#include <math.h>

#define Bn 512
#define Ln 200
#define En 64
#define Hn 4
#define Dn 16
#define KS3 18            // Kh/Qh row stride (halves): 36 B = 9 words (odd -> conflict-free)
#define VS3 200           // Vt row stride (halves): 100 words (2-way = free)
#define QSC 0.36067376022224085f   // 0.25 * log2(e): folds softmax exp into 2^x

typedef _Float16 __f16;
typedef __f16 f16x4 __attribute__((ext_vector_type(4)));
typedef __f16 f16x8 __attribute__((ext_vector_type(8)));
typedef float f32x4 __attribute__((ext_vector_type(4)));

#if __has_builtin(__builtin_amdgcn_exp2f)
__device__ __forceinline__ float fexp2(float x) { return __builtin_amdgcn_exp2f(x); }
#else
__device__ __forceinline__ float fexp2(float x) { return exp2f(x); }
#endif

__device__ __forceinline__ f16x8 pack8s(float4 a, float4 b, float4 pa, float4 pb) {
    f16x8 r;
    r[0] = (__f16)(a.x + pa.x); r[1] = (__f16)(a.y + pa.y);
    r[2] = (__f16)(a.z + pa.z); r[3] = (__f16)(a.w + pa.w);
    r[4] = (__f16)(b.x + pb.x); r[5] = (__f16)(b.y + pb.y);
    r[6] = (__f16)(b.z + pb.z); r[7] = (__f16)(b.w + pb.w);
    return r;
}
__device__ __forceinline__ f16x8 pack8(float4 a, float4 b) {
    f16x8 r;
    r[0] = (__f16)a.x; r[1] = (__f16)a.y; r[2] = (__f16)a.z; r[3] = (__f16)a.w;
    r[4] = (__f16)b.x; r[5] = (__f16)b.y; r[6] = (__f16)b.z; r[7] = (__f16)b.w;
    return r;
}

// ============ Fully fused: proj + attention + pool + Wf. Block = (b, ONE head), 256 thr ============
// R12 skeleton with the attention inner loop put on a VALU/chain diet:
//  - softmax denominator l = rowsum(P) computed by MFMA(A=ones, B=pf): every lane holds l[q=ln16]
//    replicated -> no per-kt adds, NO cross-lane shuffles for l at all.
//  - exp masked only on the true last key tile (full tiles: no cselects).
//  - lred exchange + its barrier skipped entirely when nkh==1 (block-uniform branch).
// S^T=K*Q^T C-layout == PV B-layout == lsum B-layout (proven R6-R12): no transforms.
__global__ __launch_bounds__(256, 4) void fused_kernel(
    const float* __restrict__ input, const int* __restrict__ mask,
    const float* __restrict__ pos_enc,
    const float* __restrict__ Wk, const float* __restrict__ bk,
    const float* __restrict__ Wv, const float* __restrict__ bv,
    const float* __restrict__ Wq, const float* __restrict__ bq,
    const float* __restrict__ Wf, const float* __restrict__ bf_,
    float* __restrict__ out)
{
    __shared__ __align__(16) __f16 Kh[Ln * KS3];    // 7.2 KB  K[t][16]
    __shared__ __align__(16) __f16 Qh[Ln * KS3];    // 7.2 KB  Q[t][16] (pre-scaled QSC)
    __shared__ __align__(16) __f16 Vt[16 * VS3];    // 6.4 KB  V^T[vd][t]
    __shared__ float lred[4][4][16];                // 1 KB   partial softmax denominators
    __shared__ float red[4][16];
    __shared__ float ph[16];
    __shared__ int cnt_red[4];

    const int tid  = threadIdx.x;
    const int b    = blockIdx.x >> 2, h = blockIdx.x & 3;
    const int wave = tid >> 6, lane = tid & 63;
    const int quad = lane >> 4, ln16 = lane & 15;

    // ---- mask load (1 per thread) issued first ----
    const int mv = (tid < Ln) ? mask[b * Ln + tid] : 0;

    // ---- weight B-fragments for THIS head (16 channels; L2-hot) + biases ----
    f16x8 bfr[3][2];
    #pragma unroll
    for (int m = 0; m < 3; ++m) {
        const float* W = (m == 0) ? Wk : (m == 1) ? Wv : Wq;
        #pragma unroll
        for (int ks = 0; ks < 2; ++ks) {
            const float4* wp = (const float4*)(W + (size_t)(h * 16 + ln16) * 64) + (ks * 8 + quad * 2);
            bfr[m][ks] = pack8(wp[0], wp[1]);
        }
    }
    const int cg = h * 16 + ln16;
    const float bkv = bk[cg], bvv = bv[cg], bqv = bq[cg];

    // ---- len before proj (proj is len-dependent) ----
    int c = (mv != 0) ? 1 : 0;
    #pragma unroll
    for (int off = 32; off; off >>= 1) c += __shfl_down(c, off, 64);
    if (lane == 0) cnt_red[wave] = c;
    __syncthreads();
    const int len = cnt_red[0] + cnt_red[1] + cnt_red[2] + cnt_red[3];
    const int nt = (len + 15) >> 4;

    // ---- projection over nt tiles; A-frags direct from global ----
    const float4* in4 = (const float4*)(input + (size_t)b * Ln * En);
    const float4* pe4 = (const float4*)pos_enc;

    for (int rt = wave; rt < nt; rt += 4) {
        const int R = rt * 16 + ln16;
        const bool rok = (R < Ln);
        f16x8 af[2];
        #pragma unroll
        for (int ks = 0; ks < 2; ++ks) {
            float4 xa = {0,0,0,0}, xb = {0,0,0,0}, pa = {0,0,0,0}, pb = {0,0,0,0};
            if (rok) {
                const int o4 = R * 16 + ks * 8 + quad * 2;
                xa = in4[o4]; xb = in4[o4 + 1];
                pa = pe4[o4]; pb = pe4[o4 + 1];
            }
            af[ks] = pack8s(xa, xb, pa, pb);
        }
        f32x4 acc[3];
        #pragma unroll
        for (int m = 0; m < 3; ++m) acc[m] = (f32x4){0,0,0,0};
        #pragma unroll
        for (int ks = 0; ks < 2; ++ks)
            #pragma unroll
            for (int m = 0; m < 3; ++m)
                acc[m] = __builtin_amdgcn_mfma_f32_16x16x32_f16(af[ks], bfr[m][ks], acc[m], 0, 0, 0);

        #pragma unroll
        for (int j = 0; j < 4; ++j) {
            const int t = rt * 16 + quad * 4 + j;
            if (t < Ln) {
                Kh[t * KS3 + ln16] = (__f16)(acc[0][j] + bkv);
                Qh[t * KS3 + ln16] = (__f16)((acc[2][j] + bqv) * QSC);
            }
        }
        const int vc0 = rt * 16 + quad * 4;
        if (vc0 < Ln) {
            f16x4 vp;
            #pragma unroll
            for (int j = 0; j < 4; ++j) vp[j] = (__f16)(acc[1][j] + bvv);
            *(f16x4*)(Vt + ln16 * VS3 + vc0) = vp;
        }
    }
    __syncthreads();   // K/Q/V visible

    // ---- attention: adaptive wave assignment over q-quads / key-splits ----
    const int nquad = (nt + 3) >> 2;
    int g, kh, nkh;
    if (nquad >= 3)      { g = wave;     kh = 0;         nkh = 1; }
    else if (nquad == 2) { g = wave & 1; kh = wave >> 1; nkh = 2; }
    else                 { g = 0;        kh = wave;      nkh = 4; }
    const bool active = (g < nquad);
    const int nktp = (nt + nkh - 1) / nkh;
    const int klo = kh * nktp;
    const int khi = min(klo + nktp, nt);
    const int qt0 = 4 * g;

    const f16x4 ones = {(__f16)1.f, (__f16)1.f, (__f16)1.f, (__f16)1.f};
    f32x4 o2[4], lacc[4];
    #pragma unroll
    for (int i = 0; i < 4; ++i) { o2[i] = (f32x4){0,0,0,0}; lacc[i] = (f32x4){0,0,0,0}; }

    if (active && klo < khi) {
        f16x4 qf[4];
        #pragma unroll
        for (int i = 0; i < 4; ++i) {
            int qr = min((qt0 + i) * 16 + ln16, Ln - 1);
            qf[i] = *(const f16x4*)(Qh + qr * KS3 + quad * 4);
        }
        // mask only the true last key tile (contains keys >= len)
        const bool needmask = (khi == nt);
        const int kfull = khi - (needmask ? 1 : 0);

        f16x4 kf = *(const f16x4*)(Kh + min(klo * 16 + ln16, Ln - 1) * KS3 + quad * 4);
        f16x4 vf = *(const f16x4*)(Vt + ln16 * VS3 + min(klo * 16 + quad * 4, Ln - 4));

        for (int kt = klo; kt < kfull; ++kt) {   // full tiles: no masking
            const int krn = min((kt + 1) * 16 + ln16, Ln - 1);
            const int vcn = min((kt + 1) * 16 + quad * 4, Ln - 4);
            const f16x4 kfn = *(const f16x4*)(Kh + krn * KS3 + quad * 4);
            const f16x4 vfn = *(const f16x4*)(Vt + ln16 * VS3 + vcn);
            f32x4 s[4];
            #pragma unroll
            for (int i = 0; i < 4; ++i)
                s[i] = __builtin_amdgcn_mfma_f32_16x16x16f16(kf, qf[i], (f32x4){0,0,0,0}, 0, 0, 0);
            f16x4 pf[4];
            #pragma unroll
            for (int i = 0; i < 4; ++i) {
                #pragma unroll
                for (int j = 0; j < 4; ++j)
                    pf[i][j] = (__f16)fexp2(fminf(s[i][j], 14.5f));   // 2^14.5 < fp16 max
            }
            #pragma unroll
            for (int i = 0; i < 4; ++i) {
                o2[i]   = __builtin_amdgcn_mfma_f32_16x16x16f16(vf,   pf[i], o2[i],   0, 0, 0);
                lacc[i] = __builtin_amdgcn_mfma_f32_16x16x16f16(ones, pf[i], lacc[i], 0, 0, 0);  // rowsum
            }
            kf = kfn; vf = vfn;
        }
        if (needmask) {   // last tile: zero keys >= len
            const int kbase = (nt - 1) * 16 + quad * 4;
            f32x4 s[4];
            #pragma unroll
            for (int i = 0; i < 4; ++i)
                s[i] = __builtin_amdgcn_mfma_f32_16x16x16f16(kf, qf[i], (f32x4){0,0,0,0}, 0, 0, 0);
            f16x4 pf[4];
            #pragma unroll
            for (int i = 0; i < 4; ++i) {
                #pragma unroll
                for (int j = 0; j < 4; ++j) {
                    const bool kok = (kbase + j) < len;
                    pf[i][j] = kok ? (__f16)fexp2(fminf(s[i][j], 14.5f)) : (__f16)0.f;
                }
            }
            #pragma unroll
            for (int i = 0; i < 4; ++i) {
                o2[i]   = __builtin_amdgcn_mfma_f32_16x16x16f16(vf,   pf[i], o2[i],   0, 0, 0);
                lacc[i] = __builtin_amdgcn_mfma_f32_16x16x16f16(ones, pf[i], lacc[i], 0, 0, 0);
            }
        }
    }

    // ---- denominators: lacc[i][0] = l[q=ln16] (replicated across rows by ones-MFMA) ----
    float l[4];
    #pragma unroll
    for (int i = 0; i < 4; ++i) l[i] = lacc[i][0];

    if (nkh > 1) {   // block-uniform: exchange partial denominators across key-split waves
        if (lane < 16) {
            #pragma unroll
            for (int i = 0; i < 4; ++i) lred[wave][i][lane] = l[i];
        }
        __syncthreads();
        #pragma unroll
        for (int i = 0; i < 4; ++i) {
            if (nkh == 2) l[i] = lred[g][i][ln16] + lred[g + 2][i][ln16];
            else          l[i] = lred[0][i][ln16] + lred[1][i][ln16]
                               + lred[2][i][ln16] + lred[3][i][ln16];
        }
    }

    f32x4 pool = {0.f, 0.f, 0.f, 0.f};
    if (active) {
        #pragma unroll
        for (int i = 0; i < 4; ++i) {
            const float rs = ((qt0 + i) * 16 + ln16 < len) ? 1.f / l[i] : 0.f;
            #pragma unroll
            for (int j = 0; j < 4; ++j) pool[j] = fmaf(o2[i][j], rs, pool[j]);
        }
    }

    // ---- reduce pool over 16 q-lanes; combine 4 waves; write ----
    #pragma unroll
    for (int j = 0; j < 4; ++j) {
        #pragma unroll
        for (int off = 1; off < 16; off <<= 1) pool[j] += __shfl_xor(pool[j], off, 64);
    }
    if (ln16 == 0) {
        #pragma unroll
        for (int j = 0; j < 4; ++j) red[wave][quad * 4 + j] = pool[j];
    }
    __syncthreads();
    if (tid < 16)
        ph[tid] = (red[0][tid] + red[1][tid] + red[2][tid] + red[3][tid]) / ((float)len + 1e-8f);
    __syncthreads();

    // ---- fused final projection: partial out[b,e] over i in [h*16, h*16+16) ----
    if (tid < 64) {
        const int e = tid;
        const float* wr = Wf + (size_t)e * 64 + h * 16;
        float a = (h == 0) ? bf_[e] : 0.f;
        #pragma unroll
        for (int i = 0; i < 16; ++i) a = fmaf(wr[i], ph[i], a);
        atomicAdd(out + b * En + e, a);
    }
}

extern "C" void kernel_launch(void* const* d_in, const int* in_sizes, int n_in,
                              void* d_out, int out_size, void* d_ws, size_t ws_size,
                              hipStream_t stream) {
    const float* input   = (const float*)d_in[0];
    const int*   mask    = (const int*)  d_in[1];
    const float* pos_enc = (const float*)d_in[2];
    const float* Wk      = (const float*)d_in[3];
    const float* bk      = (const float*)d_in[4];
    const float* Wv      = (const float*)d_in[5];
    const float* bv      = (const float*)d_in[6];
    const float* Wq      = (const float*)d_in[7];
    const float* bq      = (const float*)d_in[8];
    const float* Wf      = (const float*)d_in[9];
    const float* bf      = (const float*)d_in[10];

    float* out = (float*)d_out;
    hipMemsetAsync(out, 0, (size_t)Bn * En * sizeof(float), stream);   // zero accumulator

    fused_kernel<<<Bn * Hn, 256, 0, stream>>>(input, mask, pos_enc,
                                              Wk, bk, Wv, bv, Wq, bq, Wf, bf, out);
}